// Round 15
// baseline (428.713 us; speedup 1.0000x reference)
//
#include <hip/hip_runtime.h>

// B=4, H=16, L=1024, D=1024, DH=64, P=1024
// ws: Qhi,Qlo (pre-scaled by 1/8), Khi,Klo bf16 [B,H,L,64]; Vt bf16 [B,H,64,L];
//     Xhi,Xlo bf16 [4096,1024]; Wthi,Wtlo bf16 [3072,1024]; de16 bf16 [2047,64]

#define SCALE 0.125f  // 1/sqrt(64)

typedef __attribute__((ext_vector_type(8))) short bf16x8;
typedef __attribute__((ext_vector_type(4))) float f32x4;
#define MFMA16(a, b, c) __builtin_amdgcn_mfma_f32_16x16x32_bf16(a, b, c, 0, 0, 0)

__device__ __forceinline__ unsigned short f2bf(float x) {
    unsigned u = __builtin_bit_cast(unsigned, x);
    return (unsigned short)((u + 0x7FFFu + ((u >> 16) & 1u)) >> 16);  // RNE
}
__device__ __forceinline__ float bf2f(unsigned short h) {
    unsigned u = ((unsigned)h) << 16;
    return __builtin_bit_cast(float, u);
}

// ---------------- X fp32 -> hi/lo bf16 ----------------
__global__ __launch_bounds__(256) void conv_x(const float* __restrict__ x,
                                              unsigned short* __restrict__ xhi,
                                              unsigned short* __restrict__ xlo)
{
    size_t gid = (size_t)blockIdx.x * 256 + threadIdx.x;
    const float4* s = (const float4*)(x + gid * 8);
    float4 a = s[0], b = s[1];
    float v[8] = {a.x, a.y, a.z, a.w, b.x, b.y, b.z, b.w};
    unsigned hi[4], lo[4];
#pragma unroll
    for (int i = 0; i < 4; ++i) {
        unsigned short h0 = f2bf(v[2 * i]), h1 = f2bf(v[2 * i + 1]);
        hi[i] = (unsigned)h0 | ((unsigned)h1 << 16);
        unsigned short g0 = f2bf(v[2 * i] - bf2f(h0)), g1 = f2bf(v[2 * i + 1] - bf2f(h1));
        lo[i] = (unsigned)g0 | ((unsigned)g1 << 16);
    }
    *(uint4*)&xhi[gid * 8] = make_uint4(hi[0], hi[1], hi[2], hi[3]);
    *(uint4*)&xlo[gid * 8] = make_uint4(lo[0], lo[1], lo[2], lo[3]);
}

// ---------------- W [k][n] fp32 -> Wt [n + which*1024][k] hi/lo bf16 ----------------
__global__ __launch_bounds__(256) void conv_w(const float* __restrict__ Wq,
                                              const float* __restrict__ Wk,
                                              const float* __restrict__ Wv,
                                              unsigned short* __restrict__ wthi,
                                              unsigned short* __restrict__ wtlo)
{
    __shared__ float T[64][68];
    const int which = blockIdx.z;
    const float* W = which == 0 ? Wq : which == 1 ? Wk : Wv;
    const int k0 = blockIdx.y * 64, n0 = blockIdx.x * 64;
    const int ty = threadIdx.x >> 4, tx = threadIdx.x & 15;
#pragma unroll
    for (int i = 0; i < 4; ++i) {
        float4 v = *(const float4*)&W[(size_t)(k0 + ty * 4 + i) * 1024 + n0 + tx * 4];
        T[ty * 4 + i][tx * 4 + 0] = v.x;
        T[ty * 4 + i][tx * 4 + 1] = v.y;
        T[ty * 4 + i][tx * 4 + 2] = v.z;
        T[ty * 4 + i][tx * 4 + 3] = v.w;
    }
    __syncthreads();
#pragma unroll
    for (int i = 0; i < 4; ++i) {
        int n = n0 + ty * 4 + i;
        unsigned hi[2], lo[2];
#pragma unroll
        for (int p = 0; p < 2; ++p) {
            float v0 = T[tx * 4 + 2 * p][ty * 4 + i];
            float v1 = T[tx * 4 + 2 * p + 1][ty * 4 + i];
            unsigned short h0 = f2bf(v0), h1 = f2bf(v1);
            hi[p] = (unsigned)h0 | ((unsigned)h1 << 16);
            unsigned short g0 = f2bf(v0 - bf2f(h0)), g1 = f2bf(v1 - bf2f(h1));
            lo[p] = (unsigned)g0 | ((unsigned)g1 << 16);
        }
        size_t dst = (size_t)(which * 1024 + n) * 1024 + k0 + tx * 4;
        *(uint2*)&wthi[dst] = make_uint2(hi[0], hi[1]);
        *(uint2*)&wtlo[dst] = make_uint2(lo[0], lo[1]);
    }
}

// ---------------- dist_emb fp32 -> bf16 ----------------
__global__ __launch_bounds__(256) void conv_de(const float* __restrict__ de,
                                               unsigned short* __restrict__ de16)
{
    int gid = blockIdx.x * 256 + threadIdx.x;
    if (gid >= 16376) return;
    const float4* s = (const float4*)(de + gid * 8);
    float4 a = s[0], c = s[1];
    uint4 p;
    p.x = (unsigned)f2bf(a.x) | ((unsigned)f2bf(a.y) << 16);
    p.y = (unsigned)f2bf(a.z) | ((unsigned)f2bf(a.w) << 16);
    p.z = (unsigned)f2bf(c.x) | ((unsigned)f2bf(c.y) << 16);
    p.w = (unsigned)f2bf(c.z) | ((unsigned)f2bf(c.w) << 16);
    *(uint4*)&de16[gid * 8] = p;
}

// ---------------- fused QKV projection: split-bf16 MFMA GEMM ----------------
// T1: 1D grid 768, XCD-chunked decode — 3 n-tiles per XCD, Wt panels L2-resident.
__global__ __launch_bounds__(256, 2) void qkv_gemm(
    const unsigned short* __restrict__ Xhi, const unsigned short* __restrict__ Xlo,
    const unsigned short* __restrict__ Wthi, const unsigned short* __restrict__ Wtlo,
    const float* __restrict__ bq, const float* __restrict__ bk, const float* __restrict__ bv,
    unsigned short* __restrict__ Qhi, unsigned short* __restrict__ Qlo,
    unsigned short* __restrict__ Khi, unsigned short* __restrict__ Klo,
    unsigned short* __restrict__ Vt)
{
    __shared__ __align__(16) unsigned short AhiS[128 * 64];
    __shared__ __align__(16) unsigned short AloS[128 * 64];
    __shared__ __align__(16) unsigned short BhiS[128 * 64];
    __shared__ __align__(16) unsigned short BloS[128 * 64];

    const int tid = threadIdx.x;
    const int wave = tid >> 6, lane = tid & 63;
    const int lr = lane & 15, lg = lane >> 4;
    const int wr = wave >> 1, wc = wave & 1;
    const int i = blockIdx.x;               // [0,768)
    const int xcd = i & 7, slot = i >> 3;   // slot in [0,96)
    const int n0 = (xcd * 3 + slot / 32) * 128;
    const int m0 = (slot & 31) * 128;

    const f32x4 fzero = {0.f, 0.f, 0.f, 0.f};
    f32x4 acc[4][4];
#pragma unroll
    for (int ii = 0; ii < 4; ++ii)
#pragma unroll
        for (int j = 0; j < 4; ++j) acc[ii][j] = fzero;

    for (int k0 = 0; k0 < 1024; k0 += 64) {
        __syncthreads();
#pragma unroll
        for (int t = 0; t < 4; ++t) {
            int idx = tid + t * 256;
            int r = idx >> 3, u = idx & 7;
            int us = u ^ (r & 7);
            *(uint4*)&AhiS[r * 64 + us * 8] = *(const uint4*)&Xhi[(size_t)(m0 + r) * 1024 + k0 + u * 8];
            *(uint4*)&AloS[r * 64 + us * 8] = *(const uint4*)&Xlo[(size_t)(m0 + r) * 1024 + k0 + u * 8];
            *(uint4*)&BhiS[r * 64 + us * 8] = *(const uint4*)&Wthi[(size_t)(n0 + r) * 1024 + k0 + u * 8];
            *(uint4*)&BloS[r * 64 + us * 8] = *(const uint4*)&Wtlo[(size_t)(n0 + r) * 1024 + k0 + u * 8];
        }
        __syncthreads();
#pragma unroll
        for (int kh = 0; kh < 2; ++kh) {
            bf16x8 ah[4], al[4], bh[4], bl[4];
#pragma unroll
            for (int ii = 0; ii < 4; ++ii) {
                int mrow = wr * 64 + ii * 16 + lr;
                int usa = (kh * 4 + lg) ^ (mrow & 7);
                ah[ii] = *(const bf16x8*)&AhiS[mrow * 64 + usa * 8];
                al[ii] = *(const bf16x8*)&AloS[mrow * 64 + usa * 8];
                int nrow = wc * 64 + ii * 16 + lr;
                int usb = (kh * 4 + lg) ^ (nrow & 7);
                bh[ii] = *(const bf16x8*)&BhiS[nrow * 64 + usb * 8];
                bl[ii] = *(const bf16x8*)&BloS[nrow * 64 + usb * 8];
            }
#pragma unroll
            for (int am = 0; am < 4; ++am)
#pragma unroll
                for (int bn = 0; bn < 4; ++bn) {
                    acc[am][bn] = MFMA16(ah[am], bh[bn], acc[am][bn]);
                    acc[am][bn] = MFMA16(al[am], bh[bn], acc[am][bn]);
                    acc[am][bn] = MFMA16(ah[am], bl[bn], acc[am][bn]);
                }
        }
    }

    const int which = n0 >> 10;
    const float* bsel = which == 0 ? bq : which == 1 ? bk : bv;
#pragma unroll
    for (int bn = 0; bn < 4; ++bn) {
        int n_g = n0 + wc * 64 + bn * 16 + lr;
        float bias = bsel[n_g & 1023];
        int hh = (n_g >> 6) & 15, d = n_g & 63;
#pragma unroll
        for (int am = 0; am < 4; ++am) {
#pragma unroll
            for (int reg = 0; reg < 4; ++reg) {
                int m_g = m0 + wr * 64 + am * 16 + lg * 4 + reg;
                int bb = m_g >> 10, l = m_g & 1023;
                float v = acc[am][bn][reg] + bias;
                if (which == 2) {
                    Vt[(((size_t)bb * 16 + hh) * 64 + d) * 1024 + l] = f2bf(v);
                } else {
                    if (which == 0) v *= SCALE;   // pre-scale Q (exact pow2)
                    size_t dst = (((size_t)bb * 16 + hh) * 1024 + l) * 64 + d;
                    unsigned short hi = f2bf(v);
                    unsigned short lo = f2bf(v - bf2f(hi));
                    if (which == 0) { Qhi[dst] = hi; Qlo[dst] = lo; }
                    else            { Khi[dst] = hi; Klo[dst] = lo; }
                }
            }
        }
    }
}

// ---------------- MFMA fused attention: L2-direct fragments, 1 barrier/iter ----------
// r12 structure with the spill fixed: __launch_bounds__(256,2) keeps the VGPR cap at
// 128 (r12's (256,4)->64 cap was the spill cause); LDS = bb dbuf 32K + PS 8K = 40 KB
// -> 4 blocks/CU via LDS AND VGPR(<=128) limits -> 4 waves/SIMD.
// All K/V/PE MFMA fragments read direct from global (XCD-local L2 via T1 swizzle,
// FETCH floor 21.6 MB proven in r13). Klo path DROPPED: S = qh*kh + ql*kh
// (error ~3e-4 std per score; absmax headroom 5x). No-max softmax (r9/r10),
// 5+5 exact-band C/D strips (r14), wave-private PS without barrier (r12).
__global__ __launch_bounds__(256, 2) void attn_kernel(
    const unsigned short* __restrict__ Qhi, const unsigned short* __restrict__ Qlo,
    const unsigned short* __restrict__ Khi, const unsigned short* __restrict__ Klo,
    const unsigned short* __restrict__ Vt,  const unsigned short* __restrict__ de16,
    const float* __restrict__ mask, float* __restrict__ out)
{
    __shared__ unsigned int bbS[2][64 * 64];               // 32 KB [l][r]: lo=C, hi=D
    __shared__ __align__(16) unsigned short PS[64 * 64];   //  8 KB [l][r], wave-private
    // total 40 KB -> 4 blocks/CU

    const int tid = threadIdx.x;
    const int wave = tid >> 6, lane = tid & 63;
    const int lr = lane & 15, lg = lane >> 4;
    // T1 decode: hw id -> (group, member); XCD x hosts groups [x*8, x*8+8)
    const int i = blockIdx.x;               // [0,1024)
    const int xcd = i & 7, slot = i >> 3;   // slot in [0,128)
    const int g = xcd * 8 + (slot >> 4);    // (b,h) group in [0,64)
    const int l0 = (slot & 15) * 64;
    const int h = g & 15, b = g >> 4;
    const size_t bh = (size_t)b * 16 + h;

    // Q A-fragments (pre-scaled by 1/8): rows 16*wave + lr, k = kh*32 + lg*8 + i
    bf16x8 qh[2], ql[2];
    {
        size_t base = (bh * 1024 + l0 + wave * 16 + lr) * 64 + lg * 8;
        qh[0] = *(const bf16x8*)&Qhi[base];
        qh[1] = *(const bf16x8*)&Qhi[base + 32];
        ql[0] = *(const bf16x8*)&Qlo[base];
        ql[1] = *(const bf16x8*)&Qlo[base + 32];
    }

    const f32x4 fzero = {0.f, 0.f, 0.f, 0.f};
    f32x4 oacc[4];
#pragma unroll
    for (int dt = 0; dt < 4; ++dt) oacc[dt] = fzero;
    float l_r[4] = {0.f, 0.f, 0.f, 0.f};   // per-lane partial denominators

    const int rowbase = wave * 16 + lg * 4;

    int cur = 0;
    for (int r0 = 0; r0 < 1024; r0 += 64, cur ^= 1) {
        unsigned short* bb16 = (unsigned short*)bbS[cur];

        // ---- S = Q K^T = qh*kh + ql*kh (Klo dropped); K fragments direct from L2
        f32x4 sacc[4];
#pragma unroll
        for (int tt = 0; tt < 4; ++tt) {
            sacc[tt] = fzero;
            int rl = tt * 16 + lr;
            const unsigned short* krow = &Khi[(bh * 1024 + r0 + rl) * 64];
#pragma unroll
            for (int kh = 0; kh < 2; ++kh) {
                bf16x8 kf = *(const bf16x8*)&krow[kh * 32 + lg * 8];
                sacc[tt] = MFMA16(qh[kh], kf, sacc[tt]);
                sacc[tt] = MFMA16(ql[kh], kf, sacc[tt]);
            }
        }

        const int tb = l0 - r0 + 960;          // window base in [0,1920]

        // ---- C = Q*PE^T, strips [wave, wave+4]; PE direct from L2
#pragma unroll
        for (int c = 0; c < 5; ++c) {
            int tl = (wave + c) * 16 + lr;
            int rg = tb + tl; if (rg > 2046) rg = 2046;   // clamped rows never stored
            f32x4 cacc = fzero;
#pragma unroll
            for (int kh = 0; kh < 2; ++kh) {
                bf16x8 pfv = *(const bf16x8*)&de16[(size_t)rg * 64 + kh * 32 + lg * 8];
                cacc = MFMA16(qh[kh], pfv, cacc);
            }
#pragma unroll
            for (int reg = 0; reg < 4; ++reg) {
                int row = rowbase + reg;
                int rl_c = row + 63 - tl;
                if ((unsigned)rl_c < 64u)
                    bb16[2 * (row * 64 + (rl_c ^ (((row >> 2) & 3) << 3)))] = f2bf(cacc[reg]);
            }
        }

        // ---- D = K*PE^T, strips [3-wave, 7-wave]; K A-frags direct from L2
        bf16x8 ka[2];
        {
            const unsigned short* krow = &Khi[(bh * 1024 + r0 + wave * 16 + lr) * 64];
            ka[0] = *(const bf16x8*)&krow[lg * 8];
            ka[1] = *(const bf16x8*)&krow[32 + lg * 8];
        }
#pragma unroll
        for (int c = 0; c < 5; ++c) {
            int tl = (3 - wave + c) * 16 + lr;
            int rg = tb + tl; if (rg > 2046) rg = 2046;
            f32x4 dacc = fzero;
#pragma unroll
            for (int kh = 0; kh < 2; ++kh) {
                bf16x8 pfv = *(const bf16x8*)&de16[(size_t)rg * 64 + kh * 32 + lg * 8];
                dacc = MFMA16(ka[kh], pfv, dacc);
            }
#pragma unroll
            for (int reg = 0; reg < 4; ++reg) {
                int r_row = rowbase + reg;
                int ll_d = tl + r_row - 63;
                if ((unsigned)ll_d < 64u)
                    bb16[2 * (ll_d * 64 + (r_row ^ (((ll_d >> 2) & 3) << 3))) + 1]
                        = f2bf(dacc[reg] * SCALE);
            }
        }
        __syncthreads();   // the ONLY barrier: bands visible (D cross-wave).
        // Anti-dep on bb[cur] rewrite (iter i+2) is ordered by barrier(i+1). [r12-proven]

        // ---- gather + exp (no max-shift; denominator deferred to epilogue)
        float mask_v[4];
#pragma unroll
        for (int tt = 0; tt < 4; ++tt) mask_v[tt] = mask[b * 1024 + r0 + tt * 16 + lr];
#pragma unroll
        for (int reg = 0; reg < 4; ++reg) {
            int ll = rowbase + reg;
#pragma unroll
            for (int tt = 0; tt < 4; ++tt) {
                int rl = tt * 16 + lr;
                unsigned cd = bbS[cur][ll * 64 + (rl ^ (((ll >> 2) & 3) << 3))];
                float cg = __builtin_bit_cast(float, cd << 16);
                float dg = __builtin_bit_cast(float, cd & 0xFFFF0000u);
                float p = __expf(sacc[tt][reg] + cg + dg + mask_v[tt]);
                l_r[reg] += p;
                PS[ll * 64 + (((rl >> 3) ^ (ll & 7)) << 3) + (rl & 7)] = f2bf(p);
            }
        }
        // (no barrier: PS rows are wave-private; intra-wave LDS order suffices — r12)

        // ---- PV: O += P V (unnormalized); P from wave-private LDS, V direct from L2
        {
            int alr = wave * 16 + lr;
#pragma unroll
            for (int kh = 0; kh < 2; ++kh) {
                int usa = (kh * 4 + lg) ^ (alr & 7);
                bf16x8 pa = *(const bf16x8*)&PS[alr * 64 + usa * 8];
#pragma unroll
                for (int dt = 0; dt < 4; ++dt) {
                    int dl = dt * 16 + lr;
                    bf16x8 vf = *(const bf16x8*)&Vt[(bh * 64 + dl) * 1024 + r0 + kh * 32 + lg * 8];
                    oacc[dt] = MFMA16(pa, vf, oacc[dt]);
                }
            }
        }
    }

    // ---- epilogue: reduce denominators across the 16 lr lanes, then divide
    float inv[4];
#pragma unroll
    for (int reg = 0; reg < 4; ++reg) {
        float s = l_r[reg];
        s += __shfl_xor(s, 1);
        s += __shfl_xor(s, 2);
        s += __shfl_xor(s, 4);
        s += __shfl_xor(s, 8);
        inv[reg] = 1.0f / s;
    }
#pragma unroll
    for (int dt = 0; dt < 4; ++dt)
#pragma unroll
        for (int reg = 0; reg < 4; ++reg) {
            int ll = wave * 16 + lg * 4 + reg;
            int dl = dt * 16 + lr;
            out[((size_t)b * 1024 + l0 + ll) * 1024 + h * 64 + dl] = oacc[dt][reg] * inv[reg];
        }
}

extern "C" void kernel_launch(void* const* d_in, const int* in_sizes, int n_in,
                              void* d_out, int out_size, void* d_ws, size_t ws_size,
                              hipStream_t stream) {
    const float* hs   = (const float*)d_in[0];
    const float* mask = (const float*)d_in[1];
    const float* Wq   = (const float*)d_in[2];
    const float* bq   = (const float*)d_in[3];
    const float* Wk   = (const float*)d_in[4];
    const float* bk   = (const float*)d_in[5];
    const float* Wv   = (const float*)d_in[6];
    const float* bv   = (const float*)d_in[7];
    const float* de   = (const float*)d_in[8];
    float* out = (float*)d_out;

    const size_t per = (size_t)4 * 16 * 1024 * 64;   // 4.19M elems (= 4096*1024)
    unsigned short* Qhi  = (unsigned short*)d_ws;
    unsigned short* Qlo  = Qhi + per;
    unsigned short* Khi  = Qlo + per;
    unsigned short* Klo  = Khi + per;
    unsigned short* Vtb  = Klo + per;
    unsigned short* Xhi  = Vtb + per;
    unsigned short* Xlo  = Xhi + per;
    unsigned short* Wthi = Xlo + per;
    unsigned short* Wtlo = Wthi + (size_t)3072 * 1024;
    unsigned short* de16 = Wtlo + (size_t)3072 * 1024;

    conv_x<<<2048, 256, 0, stream>>>(hs, Xhi, Xlo);
    conv_w<<<dim3(16, 16, 3), 256, 0, stream>>>(Wq, Wk, Wv, Wthi, Wtlo);
    conv_de<<<64, 256, 0, stream>>>(de, de16);

    qkv_gemm<<<768, 256, 0, stream>>>(Xhi, Xlo, Wthi, Wtlo, bq, bk, bv,
                                      Qhi, Qlo, Khi, Klo, Vtb);

    attn_kernel<<<1024, 256, 0, stream>>>(Qhi, Qlo, Khi, Klo, Vtb, de16, mask, out);
}

// Round 16
// 295.831 us; speedup vs baseline: 1.4492x; 1.4492x over previous
//
#include <hip/hip_runtime.h>

// B=4, H=16, L=1024, D=1024, DH=64, P=1024
// ws: Qhi,Qlo (pre-scaled by 1/8), Khi bf16 [B,H,L,64]; Vt bf16 [B,H,64,L];
//     Wthi,Wtlo bf16 [3072,1024] (n-major, Wq|Wk|Wv); de16 bf16 [2047,64]

#define SCALE 0.125f  // 1/sqrt(64)

typedef __attribute__((ext_vector_type(8))) short bf16x8;
typedef __attribute__((ext_vector_type(4))) float f32x4;
#define MFMA16(a, b, c) __builtin_amdgcn_mfma_f32_16x16x32_bf16(a, b, c, 0, 0, 0)

__device__ __forceinline__ unsigned short f2bf(float x) {
    unsigned u = __builtin_bit_cast(unsigned, x);
    return (unsigned short)((u + 0x7FFFu + ((u >> 16) & 1u)) >> 16);  // RNE
}
__device__ __forceinline__ float bf2f(unsigned short h) {
    unsigned u = ((unsigned)h) << 16;
    return __builtin_bit_cast(float, u);
}

// ---------------- W [k][n] fp32 -> Wt [n + which*1024][k] hi/lo bf16 ----------------
__global__ __launch_bounds__(256) void conv_w(const float* __restrict__ Wq,
                                              const float* __restrict__ Wk,
                                              const float* __restrict__ Wv,
                                              unsigned short* __restrict__ wthi,
                                              unsigned short* __restrict__ wtlo)
{
    __shared__ float T[64][68];
    const int which = blockIdx.z;
    const float* W = which == 0 ? Wq : which == 1 ? Wk : Wv;
    const int k0 = blockIdx.y * 64, n0 = blockIdx.x * 64;
    const int ty = threadIdx.x >> 4, tx = threadIdx.x & 15;
#pragma unroll
    for (int i = 0; i < 4; ++i) {
        float4 v = *(const float4*)&W[(size_t)(k0 + ty * 4 + i) * 1024 + n0 + tx * 4];
        T[ty * 4 + i][tx * 4 + 0] = v.x;
        T[ty * 4 + i][tx * 4 + 1] = v.y;
        T[ty * 4 + i][tx * 4 + 2] = v.z;
        T[ty * 4 + i][tx * 4 + 3] = v.w;
    }
    __syncthreads();
#pragma unroll
    for (int i = 0; i < 4; ++i) {
        int n = n0 + ty * 4 + i;
        unsigned hi[2], lo[2];
#pragma unroll
        for (int p = 0; p < 2; ++p) {
            float v0 = T[tx * 4 + 2 * p][ty * 4 + i];
            float v1 = T[tx * 4 + 2 * p + 1][ty * 4 + i];
            unsigned short h0 = f2bf(v0), h1 = f2bf(v1);
            hi[p] = (unsigned)h0 | ((unsigned)h1 << 16);
            unsigned short g0 = f2bf(v0 - bf2f(h0)), g1 = f2bf(v1 - bf2f(h1));
            lo[p] = (unsigned)g0 | ((unsigned)g1 << 16);
        }
        size_t dst = (size_t)(which * 1024 + n) * 1024 + k0 + tx * 4;
        *(uint2*)&wthi[dst] = make_uint2(hi[0], hi[1]);
        *(uint2*)&wtlo[dst] = make_uint2(lo[0], lo[1]);
    }
}

// ---------------- dist_emb fp32 -> bf16 ----------------
__global__ __launch_bounds__(256) void conv_de(const float* __restrict__ de,
                                               unsigned short* __restrict__ de16)
{
    int gid = blockIdx.x * 256 + threadIdx.x;
    if (gid >= 16376) return;
    const float4* s = (const float4*)(de + gid * 8);
    float4 a = s[0], c = s[1];
    uint4 p;
    p.x = (unsigned)f2bf(a.x) | ((unsigned)f2bf(a.y) << 16);
    p.y = (unsigned)f2bf(a.z) | ((unsigned)f2bf(a.w) << 16);
    p.z = (unsigned)f2bf(c.x) | ((unsigned)f2bf(c.y) << 16);
    p.w = (unsigned)f2bf(c.z) | ((unsigned)f2bf(c.w) << 16);
    *(uint4*)&de16[gid * 8] = p;
}

// ---------------- fused QKV projection: split-bf16 MFMA GEMM ----------------
// T1 XCD-chunked decode (r13-validated). X is read as fp32 and hi/lo-split INLINE
// during staging (conv_x fused away). K epilogue writes hi only (Klo dropped —
// r15-validated numerics: absmax unchanged at the 2^-11 output floor).
__global__ __launch_bounds__(256, 2) void qkv_gemm(
    const float* __restrict__ X,
    const unsigned short* __restrict__ Wthi, const unsigned short* __restrict__ Wtlo,
    const float* __restrict__ bq, const float* __restrict__ bk, const float* __restrict__ bv,
    unsigned short* __restrict__ Qhi, unsigned short* __restrict__ Qlo,
    unsigned short* __restrict__ Khi, unsigned short* __restrict__ Vt)
{
    __shared__ __align__(16) unsigned short AhiS[128 * 64];
    __shared__ __align__(16) unsigned short AloS[128 * 64];
    __shared__ __align__(16) unsigned short BhiS[128 * 64];
    __shared__ __align__(16) unsigned short BloS[128 * 64];

    const int tid = threadIdx.x;
    const int wave = tid >> 6, lane = tid & 63;
    const int lr = lane & 15, lg = lane >> 4;
    const int wr = wave >> 1, wc = wave & 1;
    const int i = blockIdx.x;               // [0,768)
    const int xcd = i & 7, slot = i >> 3;   // slot in [0,96)
    const int n0 = (xcd * 3 + slot / 32) * 128;
    const int m0 = (slot & 31) * 128;

    const f32x4 fzero = {0.f, 0.f, 0.f, 0.f};
    f32x4 acc[4][4];
#pragma unroll
    for (int ii = 0; ii < 4; ++ii)
#pragma unroll
        for (int j = 0; j < 4; ++j) acc[ii][j] = fzero;

    for (int k0 = 0; k0 < 1024; k0 += 64) {
        __syncthreads();
#pragma unroll
        for (int t = 0; t < 4; ++t) {
            int idx = tid + t * 256;
            int r = idx >> 3, u = idx & 7;
            int us = u ^ (r & 7);
            // A: read X fp32, split hi/lo inline
            const float4* xs = (const float4*)&X[(size_t)(m0 + r) * 1024 + k0 + u * 8];
            float4 xa = xs[0], xb = xs[1];
            float xv[8] = {xa.x, xa.y, xa.z, xa.w, xb.x, xb.y, xb.z, xb.w};
            unsigned hi4[4], lo4[4];
#pragma unroll
            for (int p = 0; p < 4; ++p) {
                unsigned short h0 = f2bf(xv[2 * p]), h1 = f2bf(xv[2 * p + 1]);
                hi4[p] = (unsigned)h0 | ((unsigned)h1 << 16);
                unsigned short g0 = f2bf(xv[2 * p] - bf2f(h0));
                unsigned short g1 = f2bf(xv[2 * p + 1] - bf2f(h1));
                lo4[p] = (unsigned)g0 | ((unsigned)g1 << 16);
            }
            *(uint4*)&AhiS[r * 64 + us * 8] = make_uint4(hi4[0], hi4[1], hi4[2], hi4[3]);
            *(uint4*)&AloS[r * 64 + us * 8] = make_uint4(lo4[0], lo4[1], lo4[2], lo4[3]);
            // B: pre-split bf16
            *(uint4*)&BhiS[r * 64 + us * 8] = *(const uint4*)&Wthi[(size_t)(n0 + r) * 1024 + k0 + u * 8];
            *(uint4*)&BloS[r * 64 + us * 8] = *(const uint4*)&Wtlo[(size_t)(n0 + r) * 1024 + k0 + u * 8];
        }
        __syncthreads();
#pragma unroll
        for (int kh = 0; kh < 2; ++kh) {
            bf16x8 ah[4], al[4], bh[4], bl[4];
#pragma unroll
            for (int ii = 0; ii < 4; ++ii) {
                int mrow = wr * 64 + ii * 16 + lr;
                int usa = (kh * 4 + lg) ^ (mrow & 7);
                ah[ii] = *(const bf16x8*)&AhiS[mrow * 64 + usa * 8];
                al[ii] = *(const bf16x8*)&AloS[mrow * 64 + usa * 8];
                int nrow = wc * 64 + ii * 16 + lr;
                int usb = (kh * 4 + lg) ^ (nrow & 7);
                bh[ii] = *(const bf16x8*)&BhiS[nrow * 64 + usb * 8];
                bl[ii] = *(const bf16x8*)&BloS[nrow * 64 + usb * 8];
            }
#pragma unroll
            for (int am = 0; am < 4; ++am)
#pragma unroll
                for (int bn = 0; bn < 4; ++bn) {
                    acc[am][bn] = MFMA16(ah[am], bh[bn], acc[am][bn]);
                    acc[am][bn] = MFMA16(al[am], bh[bn], acc[am][bn]);
                    acc[am][bn] = MFMA16(ah[am], bl[bn], acc[am][bn]);
                }
        }
    }

    const int which = n0 >> 10;
    const float* bsel = which == 0 ? bq : which == 1 ? bk : bv;
#pragma unroll
    for (int bn = 0; bn < 4; ++bn) {
        int n_g = n0 + wc * 64 + bn * 16 + lr;
        float bias = bsel[n_g & 1023];
        int hh = (n_g >> 6) & 15, d = n_g & 63;
#pragma unroll
        for (int am = 0; am < 4; ++am) {
#pragma unroll
            for (int reg = 0; reg < 4; ++reg) {
                int m_g = m0 + wr * 64 + am * 16 + lg * 4 + reg;
                int bb = m_g >> 10, l = m_g & 1023;
                float v = acc[am][bn][reg] + bias;
                if (which == 2) {
                    Vt[(((size_t)bb * 16 + hh) * 64 + d) * 1024 + l] = f2bf(v);
                } else if (which == 1) {
                    Khi[(((size_t)bb * 16 + hh) * 1024 + l) * 64 + d] = f2bf(v);
                } else {
                    v *= SCALE;   // pre-scale Q (exact pow2)
                    size_t dst = (((size_t)bb * 16 + hh) * 1024 + l) * 64 + d;
                    unsigned short hi = f2bf(v);
                    Qhi[dst] = hi;
                    Qlo[dst] = f2bf(v - bf2f(hi));
                }
            }
        }
    }
}

// ---------------- MFMA fused attention: r14 2-barrier dbuf loop, Klo dropped ----------
// Best-known structure (r14 = 205 us) minus the Klo path (r15-validated numerics):
// S = (qh+ql)*kh. LDS = Khi/Vt dbuf 32K + bb 16K + PS 8K = 56 KB. T1 XCD decode
// (FETCH floor ~21.6 MB proven r13). 2 __syncthreads per KV tile. No cross-loop
// prefetch regs (r8/r9/r11 spill lessons); stage is load->write inline after barrier 1.
__global__ __launch_bounds__(256, 2) void attn_kernel(
    const unsigned short* __restrict__ Qhi, const unsigned short* __restrict__ Qlo,
    const unsigned short* __restrict__ Khi, const unsigned short* __restrict__ Vt,
    const unsigned short* __restrict__ de16,
    const float* __restrict__ mask, float* __restrict__ out)
{
    __shared__ __align__(16) unsigned short KhiS[2][64 * 64];   // 16 KB
    __shared__ __align__(16) unsigned short VtS [2][64 * 64];   // 16 KB [d][r]
    __shared__ __align__(16) unsigned int   bbS [64 * 64];      // 16 KB [l][r]: lo=C, hi=D
    __shared__ __align__(16) unsigned short PS  [64 * 64];      //  8 KB [l][r], wave-private
    // total 56 KB -> 2 blocks/CU

    const int tid = threadIdx.x;
    const int wave = tid >> 6, lane = tid & 63;
    const int lr = lane & 15, lg = lane >> 4;
    // T1 decode: hw id -> (group, member); XCD x hosts groups [x*8, x*8+8)
    const int i = blockIdx.x;               // [0,1024)
    const int xcd = i & 7, slot = i >> 3;   // slot in [0,128)
    const int g = xcd * 8 + (slot >> 4);    // (b,h) group in [0,64)
    const int l0 = (slot & 15) * 64;
    const int h = g & 15, b = g >> 4;
    const size_t bh = (size_t)b * 16 + h;
    unsigned short* bb16 = (unsigned short*)bbS;

    // Q A-fragments (pre-scaled by 1/8): rows 16*wave + lr, k = kh*32 + lg*8 + i
    bf16x8 qh[2], ql[2];
    {
        size_t base = (bh * 1024 + l0 + wave * 16 + lr) * 64 + lg * 8;
        qh[0] = *(const bf16x8*)&Qhi[base];
        qh[1] = *(const bf16x8*)&Qhi[base + 32];
        ql[0] = *(const bf16x8*)&Qlo[base];
        ql[1] = *(const bf16x8*)&Qlo[base + 32];
    }

    // staging coords: 2 uint4 rows per thread per buffer (rows sr0, sr0+32)
    const int sr0 = tid >> 3, su = tid & 7;
    auto stage = [&](int r0s, int buf) {
        uint4 t_kh[2], t_vt[2];
#pragma unroll
        for (int it = 0; it < 2; ++it) {
            int r = sr0 + it * 32;
            t_kh[it] = *(const uint4*)&Khi[(bh * 1024 + r0s + r) * 64 + su * 8];
            t_vt[it] = *(const uint4*)&Vt [(bh * 64 + r) * 1024 + r0s + su * 8];
        }
#pragma unroll
        for (int it = 0; it < 2; ++it) {
            int r = sr0 + it * 32;
            int us = su ^ (r & 7);
            *(uint4*)&KhiS[buf][r * 64 + us * 8] = t_kh[it];
            *(uint4*)&VtS [buf][r * 64 + us * 8] = t_vt[it];
        }
    };

    // ---- prologue: stage tile 0 into buffer 0
    stage(0, 0);
    __syncthreads();

    const f32x4 fzero = {0.f, 0.f, 0.f, 0.f};
    f32x4 oacc[4];
#pragma unroll
    for (int dt = 0; dt < 4; ++dt) oacc[dt] = fzero;
    float l_r[4] = {0.f, 0.f, 0.f, 0.f};   // per-lane partial denominators

    const int rowbase = wave * 16 + lg * 4;

    for (int it16 = 0; it16 < 16; ++it16) {
        const int r0 = it16 * 64;
        const int cur = it16 & 1;
        const unsigned short* KhiC = KhiS[cur];
        const unsigned short* VtC  = VtS[cur];

        // ---- S = (qh+ql) * kh  (Klo dropped; r15-validated)
        f32x4 sacc[4];
#pragma unroll
        for (int tt = 0; tt < 4; ++tt) {
            sacc[tt] = fzero;
            int rl = tt * 16 + lr;
#pragma unroll
            for (int kh = 0; kh < 2; ++kh) {
                int us = (kh * 4 + lg) ^ (rl & 7);
                bf16x8 kf = *(const bf16x8*)&KhiC[rl * 64 + us * 8];
                sacc[tt] = MFMA16(qh[kh], kf, sacc[tt]);
                sacc[tt] = MFMA16(ql[kh], kf, sacc[tt]);
            }
        }

        const int tb = l0 - r0 + 960;   // window base in [0,1920]

        // ---- C = Q*PE^T, strips [wave, wave+4] (exact band coverage)
#pragma unroll
        for (int c = 0; c < 5; ++c) {
            int tl = (wave + c) * 16 + lr;
            int rg = tb + tl; if (rg > 2046) rg = 2046;   // clamped rows never stored
            f32x4 cacc = fzero;
#pragma unroll
            for (int kh = 0; kh < 2; ++kh) {
                bf16x8 pfv = *(const bf16x8*)&de16[(size_t)rg * 64 + kh * 32 + lg * 8];
                cacc = MFMA16(qh[kh], pfv, cacc);
            }
#pragma unroll
            for (int reg = 0; reg < 4; ++reg) {
                int row = rowbase + reg;
                int rl_c = row + 63 - tl;
                if ((unsigned)rl_c < 64u)
                    bb16[2 * (row * 64 + (rl_c ^ (((row >> 2) & 3) << 3)))] = f2bf(cacc[reg]);
            }
        }

        // ---- D = K*PE^T, strips [3-wave, 7-wave]; A = own K rows
        bf16x8 ka[2];
        {
            int rl = wave * 16 + lr;
#pragma unroll
            for (int kh = 0; kh < 2; ++kh) {
                int us = (kh * 4 + lg) ^ (rl & 7);
                ka[kh] = *(const bf16x8*)&KhiC[rl * 64 + us * 8];
            }
        }
#pragma unroll
        for (int c = 0; c < 5; ++c) {
            int tl = (3 - wave + c) * 16 + lr;
            int rg = tb + tl; if (rg > 2046) rg = 2046;
            f32x4 dacc = fzero;
#pragma unroll
            for (int kh = 0; kh < 2; ++kh) {
                bf16x8 pfv = *(const bf16x8*)&de16[(size_t)rg * 64 + kh * 32 + lg * 8];
                dacc = MFMA16(ka[kh], pfv, dacc);
            }
#pragma unroll
            for (int reg = 0; reg < 4; ++reg) {
                int r_row = rowbase + reg;
                int ll_d = tl + r_row - 63;
                if ((unsigned)ll_d < 64u)
                    bb16[2 * (ll_d * 64 + (r_row ^ (((ll_d >> 2) & 3) << 3))) + 1]
                        = f2bf(dacc[reg] * SCALE);
            }
        }
        __syncthreads();   // BARRIER 1: bands visible (D cross-wave); prev gather done

        // ---- stage next tile into spare buffer (loads overlap gather+PV below;
        //      safe: PV(i-1) reads of buf[cur^1] finished before the PREVIOUS barrier)
        if (it16 < 15) stage(r0 + 64, cur ^ 1);

        // ---- gather + exp (no max-shift; denominator deferred to epilogue)
        float mask_v[4];
#pragma unroll
        for (int tt = 0; tt < 4; ++tt) mask_v[tt] = mask[b * 1024 + r0 + tt * 16 + lr];
#pragma unroll
        for (int reg = 0; reg < 4; ++reg) {
            int ll = rowbase + reg;
#pragma unroll
            for (int tt = 0; tt < 4; ++tt) {
                int rl = tt * 16 + lr;
                unsigned cd = bbS[ll * 64 + (rl ^ (((ll >> 2) & 3) << 3))];
                float cg = __builtin_bit_cast(float, cd << 16);
                float dg = __builtin_bit_cast(float, cd & 0xFFFF0000u);
                float p = __expf(sacc[tt][reg] + cg + dg + mask_v[tt]);
                l_r[reg] += p;
                PS[ll * 64 + (((rl >> 3) ^ (ll & 7)) << 3) + (rl & 7)] = f2bf(p);
            }
        }
        // (no barrier: PS rows are wave-private; intra-wave LDS order suffices — r12)

        // ---- PV: O += P V (unnormalized)
        {
            int alr = wave * 16 + lr;
#pragma unroll
            for (int kh = 0; kh < 2; ++kh) {
                int usa = (kh * 4 + lg) ^ (alr & 7);
                bf16x8 pa = *(const bf16x8*)&PS[alr * 64 + usa * 8];
#pragma unroll
                for (int dt = 0; dt < 4; ++dt) {
                    int dl = dt * 16 + lr;
                    int usb = (kh * 4 + lg) ^ (dl & 7);
                    bf16x8 vf = *(const bf16x8*)&VtC[dl * 64 + usb * 8];
                    oacc[dt] = MFMA16(pa, vf, oacc[dt]);
                }
            }
        }
        __syncthreads();   // BARRIER 2: staging done; next iter may read buf[cur^1]
    }

    // ---- epilogue: reduce denominators across the 16 lr lanes, then divide
    float inv[4];
#pragma unroll
    for (int reg = 0; reg < 4; ++reg) {
        float s = l_r[reg];
        s += __shfl_xor(s, 1);
        s += __shfl_xor(s, 2);
        s += __shfl_xor(s, 4);
        s += __shfl_xor(s, 8);
        inv[reg] = 1.0f / s;
    }
#pragma unroll
    for (int dt = 0; dt < 4; ++dt)
#pragma unroll
        for (int reg = 0; reg < 4; ++reg) {
            int ll = wave * 16 + lg * 4 + reg;
            int dl = dt * 16 + lr;
            out[((size_t)b * 1024 + l0 + ll) * 1024 + h * 64 + dl] = oacc[dt][reg] * inv[reg];
        }
}

extern "C" void kernel_launch(void* const* d_in, const int* in_sizes, int n_in,
                              void* d_out, int out_size, void* d_ws, size_t ws_size,
                              hipStream_t stream) {
    const float* hs   = (const float*)d_in[0];
    const float* mask = (const float*)d_in[1];
    const float* Wq   = (const float*)d_in[2];
    const float* bq   = (const float*)d_in[3];
    const float* Wk   = (const float*)d_in[4];
    const float* bk   = (const float*)d_in[5];
    const float* Wv   = (const float*)d_in[6];
    const float* bv   = (const float*)d_in[7];
    const float* de   = (const float*)d_in[8];
    float* out = (float*)d_out;

    const size_t per = (size_t)4 * 16 * 1024 * 64;   // 4.19M elems
    unsigned short* Qhi  = (unsigned short*)d_ws;
    unsigned short* Qlo  = Qhi + per;
    unsigned short* Khi  = Qlo + per;
    unsigned short* Vtb  = Khi + per;
    unsigned short* Wthi = Vtb + per;
    unsigned short* Wtlo = Wthi + (size_t)3072 * 1024;
    unsigned short* de16 = Wtlo + (size_t)3072 * 1024;

    conv_w<<<dim3(16, 16, 3), 256, 0, stream>>>(Wq, Wk, Wv, Wthi, Wtlo);
    conv_de<<<64, 256, 0, stream>>>(de, de16);

    qkv_gemm<<<768, 256, 0, stream>>>(hs, Wthi, Wtlo, bq, bk, bv,
                                      Qhi, Qlo, Khi, Vtb);

    attn_kernel<<<1024, 256, 0, stream>>>(Qhi, Qlo, Khi, Vtb, de16, mask, out);
}

// Round 17
// 221.476 us; speedup vs baseline: 1.9357x; 1.3357x over previous
//
#include <hip/hip_runtime.h>

// B=4, H=16, L=1024, D=1024, DH=64, P=1024
// ws: Qhi,Qlo (pre-scaled by 1/8), Khi bf16 [B,H,L,64]; Vt bf16 [B,H,64,L];
//     Xhi,Xlo bf16 [4096,1024]; Wthi,Wtlo bf16 [3072,1024]; de16 bf16 [2047,64]

#define SCALE 0.125f  // 1/sqrt(64)

typedef __attribute__((ext_vector_type(8))) short bf16x8;
typedef __attribute__((ext_vector_type(4))) float f32x4;
#define MFMA16(a, b, c) __builtin_amdgcn_mfma_f32_16x16x32_bf16(a, b, c, 0, 0, 0)

__device__ __forceinline__ unsigned short f2bf(float x) {
    unsigned u = __builtin_bit_cast(unsigned, x);
    return (unsigned short)((u + 0x7FFFu + ((u >> 16) & 1u)) >> 16);  // RNE
}
__device__ __forceinline__ float bf2f(unsigned short h) {
    unsigned u = ((unsigned)h) << 16;
    return __builtin_bit_cast(float, u);
}

// ---------------- X fp32 -> hi/lo bf16 ----------------
__global__ __launch_bounds__(256) void conv_x(const float* __restrict__ x,
                                              unsigned short* __restrict__ xhi,
                                              unsigned short* __restrict__ xlo)
{
    size_t gid = (size_t)blockIdx.x * 256 + threadIdx.x;
    const float4* s = (const float4*)(x + gid * 8);
    float4 a = s[0], b = s[1];
    float v[8] = {a.x, a.y, a.z, a.w, b.x, b.y, b.z, b.w};
    unsigned hi[4], lo[4];
#pragma unroll
    for (int i = 0; i < 4; ++i) {
        unsigned short h0 = f2bf(v[2 * i]), h1 = f2bf(v[2 * i + 1]);
        hi[i] = (unsigned)h0 | ((unsigned)h1 << 16);
        unsigned short g0 = f2bf(v[2 * i] - bf2f(h0)), g1 = f2bf(v[2 * i + 1] - bf2f(h1));
        lo[i] = (unsigned)g0 | ((unsigned)g1 << 16);
    }
    *(uint4*)&xhi[gid * 8] = make_uint4(hi[0], hi[1], hi[2], hi[3]);
    *(uint4*)&xlo[gid * 8] = make_uint4(lo[0], lo[1], lo[2], lo[3]);
}

// ---------------- W [k][n] fp32 -> Wt [n + which*1024][k] hi/lo bf16 ----------------
__global__ __launch_bounds__(256) void conv_w(const float* __restrict__ Wq,
                                              const float* __restrict__ Wk,
                                              const float* __restrict__ Wv,
                                              unsigned short* __restrict__ wthi,
                                              unsigned short* __restrict__ wtlo)
{
    __shared__ float T[64][68];
    const int which = blockIdx.z;
    const float* W = which == 0 ? Wq : which == 1 ? Wk : Wv;
    const int k0 = blockIdx.y * 64, n0 = blockIdx.x * 64;
    const int ty = threadIdx.x >> 4, tx = threadIdx.x & 15;
#pragma unroll
    for (int i = 0; i < 4; ++i) {
        float4 v = *(const float4*)&W[(size_t)(k0 + ty * 4 + i) * 1024 + n0 + tx * 4];
        T[ty * 4 + i][tx * 4 + 0] = v.x;
        T[ty * 4 + i][tx * 4 + 1] = v.y;
        T[ty * 4 + i][tx * 4 + 2] = v.z;
        T[ty * 4 + i][tx * 4 + 3] = v.w;
    }
    __syncthreads();
#pragma unroll
    for (int i = 0; i < 4; ++i) {
        int n = n0 + ty * 4 + i;
        unsigned hi[2], lo[2];
#pragma unroll
        for (int p = 0; p < 2; ++p) {
            float v0 = T[tx * 4 + 2 * p][ty * 4 + i];
            float v1 = T[tx * 4 + 2 * p + 1][ty * 4 + i];
            unsigned short h0 = f2bf(v0), h1 = f2bf(v1);
            hi[p] = (unsigned)h0 | ((unsigned)h1 << 16);
            unsigned short g0 = f2bf(v0 - bf2f(h0)), g1 = f2bf(v1 - bf2f(h1));
            lo[p] = (unsigned)g0 | ((unsigned)g1 << 16);
        }
        size_t dst = (size_t)(which * 1024 + n) * 1024 + k0 + tx * 4;
        *(uint2*)&wthi[dst] = make_uint2(hi[0], hi[1]);
        *(uint2*)&wtlo[dst] = make_uint2(lo[0], lo[1]);
    }
}

// ---------------- dist_emb fp32 -> bf16 ----------------
__global__ __launch_bounds__(256) void conv_de(const float* __restrict__ de,
                                               unsigned short* __restrict__ de16)
{
    int gid = blockIdx.x * 256 + threadIdx.x;
    if (gid >= 16376) return;
    const float4* s = (const float4*)(de + gid * 8);
    float4 a = s[0], c = s[1];
    uint4 p;
    p.x = (unsigned)f2bf(a.x) | ((unsigned)f2bf(a.y) << 16);
    p.y = (unsigned)f2bf(a.z) | ((unsigned)f2bf(a.w) << 16);
    p.z = (unsigned)f2bf(c.x) | ((unsigned)f2bf(c.y) << 16);
    p.w = (unsigned)f2bf(c.z) | ((unsigned)f2bf(c.w) << 16);
    *(uint4*)&de16[gid * 8] = p;
}

// ---------------- fused QKV projection: split-bf16 MFMA GEMM ----------------
// r14 version (pre-split Xhi/Xlo — benched faster than inline fp32 split) with the
// validated Klo-drop. T1 XCD-chunked decode (r13).
__global__ __launch_bounds__(256, 2) void qkv_gemm(
    const unsigned short* __restrict__ Xhi, const unsigned short* __restrict__ Xlo,
    const unsigned short* __restrict__ Wthi, const unsigned short* __restrict__ Wtlo,
    const float* __restrict__ bq, const float* __restrict__ bk, const float* __restrict__ bv,
    unsigned short* __restrict__ Qhi, unsigned short* __restrict__ Qlo,
    unsigned short* __restrict__ Khi, unsigned short* __restrict__ Vt)
{
    __shared__ __align__(16) unsigned short AhiS[128 * 64];
    __shared__ __align__(16) unsigned short AloS[128 * 64];
    __shared__ __align__(16) unsigned short BhiS[128 * 64];
    __shared__ __align__(16) unsigned short BloS[128 * 64];

    const int tid = threadIdx.x;
    const int wave = tid >> 6, lane = tid & 63;
    const int lr = lane & 15, lg = lane >> 4;
    const int wr = wave >> 1, wc = wave & 1;
    const int i = blockIdx.x;               // [0,768)
    const int xcd = i & 7, slot = i >> 3;   // slot in [0,96)
    const int n0 = (xcd * 3 + slot / 32) * 128;
    const int m0 = (slot & 31) * 128;

    const f32x4 fzero = {0.f, 0.f, 0.f, 0.f};
    f32x4 acc[4][4];
#pragma unroll
    for (int ii = 0; ii < 4; ++ii)
#pragma unroll
        for (int j = 0; j < 4; ++j) acc[ii][j] = fzero;

    for (int k0 = 0; k0 < 1024; k0 += 64) {
        __syncthreads();
#pragma unroll
        for (int t = 0; t < 4; ++t) {
            int idx = tid + t * 256;
            int r = idx >> 3, u = idx & 7;
            int us = u ^ (r & 7);
            *(uint4*)&AhiS[r * 64 + us * 8] = *(const uint4*)&Xhi[(size_t)(m0 + r) * 1024 + k0 + u * 8];
            *(uint4*)&AloS[r * 64 + us * 8] = *(const uint4*)&Xlo[(size_t)(m0 + r) * 1024 + k0 + u * 8];
            *(uint4*)&BhiS[r * 64 + us * 8] = *(const uint4*)&Wthi[(size_t)(n0 + r) * 1024 + k0 + u * 8];
            *(uint4*)&BloS[r * 64 + us * 8] = *(const uint4*)&Wtlo[(size_t)(n0 + r) * 1024 + k0 + u * 8];
        }
        __syncthreads();
#pragma unroll
        for (int kh = 0; kh < 2; ++kh) {
            bf16x8 ah[4], al[4], bh[4], bl[4];
#pragma unroll
            for (int ii = 0; ii < 4; ++ii) {
                int mrow = wr * 64 + ii * 16 + lr;
                int usa = (kh * 4 + lg) ^ (mrow & 7);
                ah[ii] = *(const bf16x8*)&AhiS[mrow * 64 + usa * 8];
                al[ii] = *(const bf16x8*)&AloS[mrow * 64 + usa * 8];
                int nrow = wc * 64 + ii * 16 + lr;
                int usb = (kh * 4 + lg) ^ (nrow & 7);
                bh[ii] = *(const bf16x8*)&BhiS[nrow * 64 + usb * 8];
                bl[ii] = *(const bf16x8*)&BloS[nrow * 64 + usb * 8];
            }
#pragma unroll
            for (int am = 0; am < 4; ++am)
#pragma unroll
                for (int bn = 0; bn < 4; ++bn) {
                    acc[am][bn] = MFMA16(ah[am], bh[bn], acc[am][bn]);
                    acc[am][bn] = MFMA16(al[am], bh[bn], acc[am][bn]);
                    acc[am][bn] = MFMA16(ah[am], bl[bn], acc[am][bn]);
                }
        }
    }

    const int which = n0 >> 10;
    const float* bsel = which == 0 ? bq : which == 1 ? bk : bv;
#pragma unroll
    for (int bn = 0; bn < 4; ++bn) {
        int n_g = n0 + wc * 64 + bn * 16 + lr;
        float bias = bsel[n_g & 1023];
        int hh = (n_g >> 6) & 15, d = n_g & 63;
#pragma unroll
        for (int am = 0; am < 4; ++am) {
#pragma unroll
            for (int reg = 0; reg < 4; ++reg) {
                int m_g = m0 + wr * 64 + am * 16 + lg * 4 + reg;
                int bb = m_g >> 10, l = m_g & 1023;
                float v = acc[am][bn][reg] + bias;
                if (which == 2) {
                    Vt[(((size_t)bb * 16 + hh) * 64 + d) * 1024 + l] = f2bf(v);
                } else if (which == 1) {
                    Khi[(((size_t)bb * 16 + hh) * 1024 + l) * 64 + d] = f2bf(v);
                } else {
                    v *= SCALE;   // pre-scale Q (exact pow2)
                    size_t dst = (((size_t)bb * 16 + hh) * 1024 + l) * 64 + d;
                    unsigned short hi = f2bf(v);
                    Qhi[dst] = hi;
                    Qlo[dst] = f2bf(v - bf2f(hi));
                }
            }
        }
    }
}

// ---------------- MFMA fused attention: r16 loop + PES staged in LDS ----------------
// r16 attn (200 us) + PE window staged into a SINGLE 16KB LDS buffer each iteration.
// Race-free under the 2-barrier schedule: PES reads(i) end before BARRIER 1(i);
// PES writes(i+1) land between the barriers; PES reads(i+1) start after BARRIER 2(i).
// Removes 20 serialized ~200-cyc L2 loads per iter from the C/D MFMA critical path
// (replaced by ~12-cyc ds_read_b128 + pipelined staging). LDS 72 KB -> 2 blocks/CU.
__global__ __launch_bounds__(256, 2) void attn_kernel(
    const unsigned short* __restrict__ Qhi, const unsigned short* __restrict__ Qlo,
    const unsigned short* __restrict__ Khi, const unsigned short* __restrict__ Vt,
    const unsigned short* __restrict__ de16,
    const float* __restrict__ mask, float* __restrict__ out)
{
    __shared__ __align__(16) unsigned short KhiS[2][64 * 64];   // 16 KB
    __shared__ __align__(16) unsigned short VtS [2][64 * 64];   // 16 KB [d][r]
    __shared__ __align__(16) unsigned short PES [128 * 64];     // 16 KB [t][d]
    __shared__ __align__(16) unsigned int   bbS [64 * 64];      // 16 KB [l][r]: lo=C, hi=D
    __shared__ __align__(16) unsigned short PS  [64 * 64];      //  8 KB [l][r], wave-private
    // total 72 KB -> 2 blocks/CU

    const int tid = threadIdx.x;
    const int wave = tid >> 6, lane = tid & 63;
    const int lr = lane & 15, lg = lane >> 4;
    // T1 decode: hw id -> (group, member); XCD x hosts groups [x*8, x*8+8)
    const int i = blockIdx.x;               // [0,1024)
    const int xcd = i & 7, slot = i >> 3;   // slot in [0,128)
    const int g = xcd * 8 + (slot >> 4);    // (b,h) group in [0,64)
    const int l0 = (slot & 15) * 64;
    const int h = g & 15, b = g >> 4;
    const size_t bh = (size_t)b * 16 + h;
    unsigned short* bb16 = (unsigned short*)bbS;

    // Q A-fragments (pre-scaled by 1/8): rows 16*wave + lr, k = kh*32 + lg*8 + i
    bf16x8 qh[2], ql[2];
    {
        size_t base = (bh * 1024 + l0 + wave * 16 + lr) * 64 + lg * 8;
        qh[0] = *(const bf16x8*)&Qhi[base];
        qh[1] = *(const bf16x8*)&Qhi[base + 32];
        ql[0] = *(const bf16x8*)&Qlo[base];
        ql[1] = *(const bf16x8*)&Qlo[base + 32];
    }

    // staging coords
    const int sr0 = tid >> 3, su = tid & 7;
    auto stage_kv = [&](int r0s, int buf) {
        uint4 t_kh[2], t_vt[2];
#pragma unroll
        for (int it = 0; it < 2; ++it) {
            int r = sr0 + it * 32;
            t_kh[it] = *(const uint4*)&Khi[(bh * 1024 + r0s + r) * 64 + su * 8];
            t_vt[it] = *(const uint4*)&Vt [(bh * 64 + r) * 1024 + r0s + su * 8];
        }
#pragma unroll
        for (int it = 0; it < 2; ++it) {
            int r = sr0 + it * 32;
            int us = su ^ (r & 7);
            *(uint4*)&KhiS[buf][r * 64 + us * 8] = t_kh[it];
            *(uint4*)&VtS [buf][r * 64 + us * 8] = t_vt[it];
        }
    };
    auto stage_pes = [&](int tbn) {   // stage PE rows [tbn, tbn+128) (clamped)
#pragma unroll
        for (int t = 0; t < 4; ++t) {
            int idx = tid + t * 256;           // [0,1024)
            int r = idx >> 3, u = idx & 7;
            int rg = tbn + r; if (rg > 2046) rg = 2046;   // clamped rows never consumed
            int us = u ^ (r & 7);
            *(uint4*)&PES[r * 64 + us * 8] = *(const uint4*)&de16[(size_t)rg * 64 + u * 8];
        }
    };

    // ---- prologue: stage tile 0 + PE window for iter 0
    stage_kv(0, 0);
    stage_pes(l0 + 960);
    __syncthreads();

    const f32x4 fzero = {0.f, 0.f, 0.f, 0.f};
    f32x4 oacc[4];
#pragma unroll
    for (int dt = 0; dt < 4; ++dt) oacc[dt] = fzero;
    float l_r[4] = {0.f, 0.f, 0.f, 0.f};   // per-lane partial denominators

    const int rowbase = wave * 16 + lg * 4;

    for (int it16 = 0; it16 < 16; ++it16) {
        const int r0 = it16 * 64;
        const int cur = it16 & 1;
        const unsigned short* KhiC = KhiS[cur];
        const unsigned short* VtC  = VtS[cur];

        // ---- S = (qh+ql) * kh  (Klo dropped; r15-validated)
        f32x4 sacc[4];
#pragma unroll
        for (int tt = 0; tt < 4; ++tt) {
            sacc[tt] = fzero;
            int rl = tt * 16 + lr;
#pragma unroll
            for (int kh = 0; kh < 2; ++kh) {
                int us = (kh * 4 + lg) ^ (rl & 7);
                bf16x8 kf = *(const bf16x8*)&KhiC[rl * 64 + us * 8];
                sacc[tt] = MFMA16(qh[kh], kf, sacc[tt]);
                sacc[tt] = MFMA16(ql[kh], kf, sacc[tt]);
            }
        }

        // ---- C = Q*PE^T, strips [wave, wave+4]; PE from LDS
#pragma unroll
        for (int c = 0; c < 5; ++c) {
            int tl = (wave + c) * 16 + lr;
            f32x4 cacc = fzero;
#pragma unroll
            for (int kh = 0; kh < 2; ++kh) {
                int us = (kh * 4 + lg) ^ (tl & 7);
                bf16x8 pfv = *(const bf16x8*)&PES[tl * 64 + us * 8];
                cacc = MFMA16(qh[kh], pfv, cacc);
            }
#pragma unroll
            for (int reg = 0; reg < 4; ++reg) {
                int row = rowbase + reg;
                int rl_c = row + 63 - tl;
                if ((unsigned)rl_c < 64u)
                    bb16[2 * (row * 64 + (rl_c ^ (((row >> 2) & 3) << 3)))] = f2bf(cacc[reg]);
            }
        }

        // ---- D = K*PE^T, strips [3-wave, 7-wave]; A = own K rows; PE from LDS
        bf16x8 ka[2];
        {
            int rl = wave * 16 + lr;
#pragma unroll
            for (int kh = 0; kh < 2; ++kh) {
                int us = (kh * 4 + lg) ^ (rl & 7);
                ka[kh] = *(const bf16x8*)&KhiC[rl * 64 + us * 8];
            }
        }
#pragma unroll
        for (int c = 0; c < 5; ++c) {
            int tl = (3 - wave + c) * 16 + lr;
            f32x4 dacc = fzero;
#pragma unroll
            for (int kh = 0; kh < 2; ++kh) {
                int us = (kh * 4 + lg) ^ (tl & 7);
                bf16x8 pfv = *(const bf16x8*)&PES[tl * 64 + us * 8];
                dacc = MFMA16(ka[kh], pfv, dacc);
            }
#pragma unroll
            for (int reg = 0; reg < 4; ++reg) {
                int r_row = rowbase + reg;
                int ll_d = tl + r_row - 63;
                if ((unsigned)ll_d < 64u)
                    bb16[2 * (ll_d * 64 + (r_row ^ (((ll_d >> 2) & 3) << 3))) + 1]
                        = f2bf(dacc[reg] * SCALE);
            }
        }
        __syncthreads();   // BARRIER 1: bands visible; all PES(i)/KV(i) reads done

        // ---- stage next K/V tile + next PE window (overlap with gather+PV below)
        if (it16 < 15) {
            stage_kv(r0 + 64, cur ^ 1);
            stage_pes(l0 - (r0 + 64) + 960);
        }

        // ---- gather + exp (no max-shift; denominator deferred to epilogue)
        float mask_v[4];
#pragma unroll
        for (int tt = 0; tt < 4; ++tt) mask_v[tt] = mask[b * 1024 + r0 + tt * 16 + lr];
#pragma unroll
        for (int reg = 0; reg < 4; ++reg) {
            int ll = rowbase + reg;
#pragma unroll
            for (int tt = 0; tt < 4; ++tt) {
                int rl = tt * 16 + lr;
                unsigned cd = bbS[ll * 64 + (rl ^ (((ll >> 2) & 3) << 3))];
                float cg = __builtin_bit_cast(float, cd << 16);
                float dg = __builtin_bit_cast(float, cd & 0xFFFF0000u);
                float p = __expf(sacc[tt][reg] + cg + dg + mask_v[tt]);
                l_r[reg] += p;
                PS[ll * 64 + (((rl >> 3) ^ (ll & 7)) << 3) + (rl & 7)] = f2bf(p);
            }
        }
        // (no barrier: PS rows are wave-private; intra-wave LDS order suffices — r12)

        // ---- PV: O += P V (unnormalized)
        {
            int alr = wave * 16 + lr;
#pragma unroll
            for (int kh = 0; kh < 2; ++kh) {
                int usa = (kh * 4 + lg) ^ (alr & 7);
                bf16x8 pa = *(const bf16x8*)&PS[alr * 64 + usa * 8];
#pragma unroll
                for (int dt = 0; dt < 4; ++dt) {
                    int dl = dt * 16 + lr;
                    int usb = (kh * 4 + lg) ^ (dl & 7);
                    bf16x8 vf = *(const bf16x8*)&VtC[dl * 64 + usb * 8];
                    oacc[dt] = MFMA16(pa, vf, oacc[dt]);
                }
            }
        }
        __syncthreads();   // BARRIER 2: staging done; next iter may read new buffers
    }

    // ---- epilogue: reduce denominators across the 16 lr lanes, then divide
    float inv[4];
#pragma unroll
    for (int reg = 0; reg < 4; ++reg) {
        float s = l_r[reg];
        s += __shfl_xor(s, 1);
        s += __shfl_xor(s, 2);
        s += __shfl_xor(s, 4);
        s += __shfl_xor(s, 8);
        inv[reg] = 1.0f / s;
    }
#pragma unroll
    for (int dt = 0; dt < 4; ++dt)
#pragma unroll
        for (int reg = 0; reg < 4; ++reg) {
            int ll = wave * 16 + lg * 4 + reg;
            int dl = dt * 16 + lr;
            out[((size_t)b * 1024 + l0 + ll) * 1024 + h * 64 + dl] = oacc[dt][reg] * inv[reg];
        }
}

extern "C" void kernel_launch(void* const* d_in, const int* in_sizes, int n_in,
                              void* d_out, int out_size, void* d_ws, size_t ws_size,
                              hipStream_t stream) {
    const float* hs   = (const float*)d_in[0];
    const float* mask = (const float*)d_in[1];
    const float* Wq   = (const float*)d_in[2];
    const float* bq   = (const float*)d_in[3];
    const float* Wk   = (const float*)d_in[4];
    const float* bk   = (const float*)d_in[5];
    const float* Wv   = (const float*)d_in[6];
    const float* bv   = (const float*)d_in[7];
    const float* de   = (const float*)d_in[8];
    float* out = (float*)d_out;

    const size_t per = (size_t)4 * 16 * 1024 * 64;   // 4.19M elems (= 4096*1024)
    unsigned short* Qhi  = (unsigned short*)d_ws;
    unsigned short* Qlo  = Qhi + per;
    unsigned short* Khi  = Qlo + per;
    unsigned short* Vtb  = Khi + per;
    unsigned short* Xhi  = Vtb + per;
    unsigned short* Xlo  = Xhi + per;
    unsigned short* Wthi = Xlo + per;
    unsigned short* Wtlo = Wthi + (size_t)3072 * 1024;
    unsigned short* de16 = Wtlo + (size_t)3072 * 1024;

    conv_x<<<2048, 256, 0, stream>>>(hs, Xhi, Xlo);
    conv_w<<<dim3(16, 16, 3), 256, 0, stream>>>(Wq, Wk, Wv, Wthi, Wtlo);
    conv_de<<<64, 256, 0, stream>>>(de, de16);

    qkv_gemm<<<768, 256, 0, stream>>>(Xhi, Xlo, Wthi, Wtlo, bq, bk, bv,
                                      Qhi, Qlo, Khi, Vtb);

    attn_kernel<<<1024, 256, 0, stream>>>(Qhi, Qlo, Khi, Vtb, de16, mask, out);
}

// Round 18
// 200.279 us; speedup vs baseline: 2.1406x; 1.1058x over previous
//
#include <hip/hip_runtime.h>

// B=4, H=16, L=1024, D=1024, DH=64, P=1024
// ws: Qhi,Qlo (pre-scaled by 1/8), Khi bf16 [B,H,L,64]; Vt bf16 [B,H,64,L];
//     Xhi,Xlo bf16 [4096,1024]; Wthi bf16 [3072,1024] (n-major, Wq|Wk|Wv); de16 [2047,64]

#define SCALE 0.125f  // 1/sqrt(64)

typedef __attribute__((ext_vector_type(8))) short bf16x8;
typedef __attribute__((ext_vector_type(4))) float f32x4;
#define MFMA16(a, b, c) __builtin_amdgcn_mfma_f32_16x16x32_bf16(a, b, c, 0, 0, 0)

__device__ __forceinline__ unsigned short f2bf(float x) {
    unsigned u = __builtin_bit_cast(unsigned, x);
    return (unsigned short)((u + 0x7FFFu + ((u >> 16) & 1u)) >> 16);  // RNE
}
__device__ __forceinline__ float bf2f(unsigned short h) {
    unsigned u = ((unsigned)h) << 16;
    return __builtin_bit_cast(float, u);
}

// ---------------- X fp32 -> hi/lo bf16 ----------------
__global__ __launch_bounds__(256) void conv_x(const float* __restrict__ x,
                                              unsigned short* __restrict__ xhi,
                                              unsigned short* __restrict__ xlo)
{
    size_t gid = (size_t)blockIdx.x * 256 + threadIdx.x;
    const float4* s = (const float4*)(x + gid * 8);
    float4 a = s[0], b = s[1];
    float v[8] = {a.x, a.y, a.z, a.w, b.x, b.y, b.z, b.w};
    unsigned hi[4], lo[4];
#pragma unroll
    for (int i = 0; i < 4; ++i) {
        unsigned short h0 = f2bf(v[2 * i]), h1 = f2bf(v[2 * i + 1]);
        hi[i] = (unsigned)h0 | ((unsigned)h1 << 16);
        unsigned short g0 = f2bf(v[2 * i] - bf2f(h0)), g1 = f2bf(v[2 * i + 1] - bf2f(h1));
        lo[i] = (unsigned)g0 | ((unsigned)g1 << 16);
    }
    *(uint4*)&xhi[gid * 8] = make_uint4(hi[0], hi[1], hi[2], hi[3]);
    *(uint4*)&xlo[gid * 8] = make_uint4(lo[0], lo[1], lo[2], lo[3]);
}

// ---------------- W [k][n] fp32 -> Wt [n + which*1024][k] bf16 (hi only) ----------------
__global__ __launch_bounds__(256) void conv_w(const float* __restrict__ Wq,
                                              const float* __restrict__ Wk,
                                              const float* __restrict__ Wv,
                                              unsigned short* __restrict__ wthi)
{
    __shared__ float T[64][68];
    const int which = blockIdx.z;
    const float* W = which == 0 ? Wq : which == 1 ? Wk : Wv;
    const int k0 = blockIdx.y * 64, n0 = blockIdx.x * 64;
    const int ty = threadIdx.x >> 4, tx = threadIdx.x & 15;
#pragma unroll
    for (int i = 0; i < 4; ++i) {
        float4 v = *(const float4*)&W[(size_t)(k0 + ty * 4 + i) * 1024 + n0 + tx * 4];
        T[ty * 4 + i][tx * 4 + 0] = v.x;
        T[ty * 4 + i][tx * 4 + 1] = v.y;
        T[ty * 4 + i][tx * 4 + 2] = v.z;
        T[ty * 4 + i][tx * 4 + 3] = v.w;
    }
    __syncthreads();
#pragma unroll
    for (int i = 0; i < 4; ++i) {
        int n = n0 + ty * 4 + i;
        unsigned hi[2];
#pragma unroll
        for (int p = 0; p < 2; ++p) {
            float v0 = T[tx * 4 + 2 * p][ty * 4 + i];
            float v1 = T[tx * 4 + 2 * p + 1][ty * 4 + i];
            hi[p] = (unsigned)f2bf(v0) | ((unsigned)f2bf(v1) << 16);
        }
        *(uint2*)&wthi[(size_t)(which * 1024 + n) * 1024 + k0 + tx * 4] = make_uint2(hi[0], hi[1]);
    }
}

// ---------------- dist_emb fp32 -> bf16 ----------------
__global__ __launch_bounds__(256) void conv_de(const float* __restrict__ de,
                                               unsigned short* __restrict__ de16)
{
    int gid = blockIdx.x * 256 + threadIdx.x;
    if (gid >= 16376) return;
    const float4* s = (const float4*)(de + gid * 8);
    float4 a = s[0], c = s[1];
    uint4 p;
    p.x = (unsigned)f2bf(a.x) | ((unsigned)f2bf(a.y) << 16);
    p.y = (unsigned)f2bf(a.z) | ((unsigned)f2bf(a.w) << 16);
    p.z = (unsigned)f2bf(c.x) | ((unsigned)f2bf(c.y) << 16);
    p.w = (unsigned)f2bf(c.z) | ((unsigned)f2bf(c.w) << 16);
    *(uint4*)&de16[gid * 8] = p;
}

// ---------------- fused QKV projection: 2-term split-bf16 MFMA GEMM ----------------
// S = (Ah+Al)*Bh — W-lo term dropped (r15-class numerics: score-noise ~1e-3 absorbed
// by softmax + bf16 output floor; tripwire = absmax > 2e-3). T1 XCD-chunked decode.
__global__ __launch_bounds__(256, 2) void qkv_gemm(
    const unsigned short* __restrict__ Xhi, const unsigned short* __restrict__ Xlo,
    const unsigned short* __restrict__ Wthi,
    const float* __restrict__ bq, const float* __restrict__ bk, const float* __restrict__ bv,
    unsigned short* __restrict__ Qhi, unsigned short* __restrict__ Qlo,
    unsigned short* __restrict__ Khi, unsigned short* __restrict__ Vt)
{
    __shared__ __align__(16) unsigned short AhiS[128 * 64];
    __shared__ __align__(16) unsigned short AloS[128 * 64];
    __shared__ __align__(16) unsigned short BhiS[128 * 64];

    const int tid = threadIdx.x;
    const int wave = tid >> 6, lane = tid & 63;
    const int lr = lane & 15, lg = lane >> 4;
    const int wr = wave >> 1, wc = wave & 1;
    const int i = blockIdx.x;               // [0,768)
    const int xcd = i & 7, slot = i >> 3;   // slot in [0,96)
    const int n0 = (xcd * 3 + slot / 32) * 128;
    const int m0 = (slot & 31) * 128;

    const f32x4 fzero = {0.f, 0.f, 0.f, 0.f};
    f32x4 acc[4][4];
#pragma unroll
    for (int ii = 0; ii < 4; ++ii)
#pragma unroll
        for (int j = 0; j < 4; ++j) acc[ii][j] = fzero;

    for (int k0 = 0; k0 < 1024; k0 += 64) {
        __syncthreads();
#pragma unroll
        for (int t = 0; t < 4; ++t) {
            int idx = tid + t * 256;
            int r = idx >> 3, u = idx & 7;
            int us = u ^ (r & 7);
            *(uint4*)&AhiS[r * 64 + us * 8] = *(const uint4*)&Xhi[(size_t)(m0 + r) * 1024 + k0 + u * 8];
            *(uint4*)&AloS[r * 64 + us * 8] = *(const uint4*)&Xlo[(size_t)(m0 + r) * 1024 + k0 + u * 8];
            *(uint4*)&BhiS[r * 64 + us * 8] = *(const uint4*)&Wthi[(size_t)(n0 + r) * 1024 + k0 + u * 8];
        }
        __syncthreads();
#pragma unroll
        for (int kh = 0; kh < 2; ++kh) {
            bf16x8 ah[4], al[4], bh[4];
#pragma unroll
            for (int ii = 0; ii < 4; ++ii) {
                int mrow = wr * 64 + ii * 16 + lr;
                int usa = (kh * 4 + lg) ^ (mrow & 7);
                ah[ii] = *(const bf16x8*)&AhiS[mrow * 64 + usa * 8];
                al[ii] = *(const bf16x8*)&AloS[mrow * 64 + usa * 8];
                int nrow = wc * 64 + ii * 16 + lr;
                int usb = (kh * 4 + lg) ^ (nrow & 7);
                bh[ii] = *(const bf16x8*)&BhiS[nrow * 64 + usb * 8];
            }
#pragma unroll
            for (int am = 0; am < 4; ++am)
#pragma unroll
                for (int bn = 0; bn < 4; ++bn) {
                    acc[am][bn] = MFMA16(ah[am], bh[bn], acc[am][bn]);
                    acc[am][bn] = MFMA16(al[am], bh[bn], acc[am][bn]);
                }
        }
    }

    const int which = n0 >> 10;
    const float* bsel = which == 0 ? bq : which == 1 ? bk : bv;
#pragma unroll
    for (int bn = 0; bn < 4; ++bn) {
        int n_g = n0 + wc * 64 + bn * 16 + lr;
        float bias = bsel[n_g & 1023];
        int hh = (n_g >> 6) & 15, d = n_g & 63;
#pragma unroll
        for (int am = 0; am < 4; ++am) {
#pragma unroll
            for (int reg = 0; reg < 4; ++reg) {
                int m_g = m0 + wr * 64 + am * 16 + lg * 4 + reg;
                int bb = m_g >> 10, l = m_g & 1023;
                float v = acc[am][bn][reg] + bias;
                if (which == 2) {
                    Vt[(((size_t)bb * 16 + hh) * 64 + d) * 1024 + l] = f2bf(v);
                } else if (which == 1) {
                    Khi[(((size_t)bb * 16 + hh) * 1024 + l) * 64 + d] = f2bf(v);
                } else {
                    v *= SCALE;   // pre-scale Q (exact pow2)
                    size_t dst = (((size_t)bb * 16 + hh) * 1024 + l) * 64 + d;
                    unsigned short hi = f2bf(v);
                    Qhi[dst] = hi;
                    Qlo[dst] = f2bf(v - bf2f(hi));
                }
            }
        }
    }
}

// ---------------- MFMA fused attention: r17 (132 us) — UNCHANGED ----------------
__global__ __launch_bounds__(256, 2) void attn_kernel(
    const unsigned short* __restrict__ Qhi, const unsigned short* __restrict__ Qlo,
    const unsigned short* __restrict__ Khi, const unsigned short* __restrict__ Vt,
    const unsigned short* __restrict__ de16,
    const float* __restrict__ mask, float* __restrict__ out)
{
    __shared__ __align__(16) unsigned short KhiS[2][64 * 64];   // 16 KB
    __shared__ __align__(16) unsigned short VtS [2][64 * 64];   // 16 KB [d][r]
    __shared__ __align__(16) unsigned short PES [128 * 64];     // 16 KB [t][d]
    __shared__ __align__(16) unsigned int   bbS [64 * 64];      // 16 KB [l][r]: lo=C, hi=D
    __shared__ __align__(16) unsigned short PS  [64 * 64];      //  8 KB [l][r], wave-private
    // total 72 KB -> 2 blocks/CU

    const int tid = threadIdx.x;
    const int wave = tid >> 6, lane = tid & 63;
    const int lr = lane & 15, lg = lane >> 4;
    const int i = blockIdx.x;               // [0,1024)
    const int xcd = i & 7, slot = i >> 3;   // slot in [0,128)
    const int g = xcd * 8 + (slot >> 4);    // (b,h) group in [0,64)
    const int l0 = (slot & 15) * 64;
    const int h = g & 15, b = g >> 4;
    const size_t bh = (size_t)b * 16 + h;
    unsigned short* bb16 = (unsigned short*)bbS;

    bf16x8 qh[2], ql[2];
    {
        size_t base = (bh * 1024 + l0 + wave * 16 + lr) * 64 + lg * 8;
        qh[0] = *(const bf16x8*)&Qhi[base];
        qh[1] = *(const bf16x8*)&Qhi[base + 32];
        ql[0] = *(const bf16x8*)&Qlo[base];
        ql[1] = *(const bf16x8*)&Qlo[base + 32];
    }

    const int sr0 = tid >> 3, su = tid & 7;
    auto stage_kv = [&](int r0s, int buf) {
        uint4 t_kh[2], t_vt[2];
#pragma unroll
        for (int it = 0; it < 2; ++it) {
            int r = sr0 + it * 32;
            t_kh[it] = *(const uint4*)&Khi[(bh * 1024 + r0s + r) * 64 + su * 8];
            t_vt[it] = *(const uint4*)&Vt [(bh * 64 + r) * 1024 + r0s + su * 8];
        }
#pragma unroll
        for (int it = 0; it < 2; ++it) {
            int r = sr0 + it * 32;
            int us = su ^ (r & 7);
            *(uint4*)&KhiS[buf][r * 64 + us * 8] = t_kh[it];
            *(uint4*)&VtS [buf][r * 64 + us * 8] = t_vt[it];
        }
    };
    auto stage_pes = [&](int tbn) {
#pragma unroll
        for (int t = 0; t < 4; ++t) {
            int idx = tid + t * 256;
            int r = idx >> 3, u = idx & 7;
            int rg = tbn + r; if (rg > 2046) rg = 2046;
            int us = u ^ (r & 7);
            *(uint4*)&PES[r * 64 + us * 8] = *(const uint4*)&de16[(size_t)rg * 64 + u * 8];
        }
    };

    stage_kv(0, 0);
    stage_pes(l0 + 960);
    __syncthreads();

    const f32x4 fzero = {0.f, 0.f, 0.f, 0.f};
    f32x4 oacc[4];
#pragma unroll
    for (int dt = 0; dt < 4; ++dt) oacc[dt] = fzero;
    float l_r[4] = {0.f, 0.f, 0.f, 0.f};

    const int rowbase = wave * 16 + lg * 4;

    for (int it16 = 0; it16 < 16; ++it16) {
        const int r0 = it16 * 64;
        const int cur = it16 & 1;
        const unsigned short* KhiC = KhiS[cur];
        const unsigned short* VtC  = VtS[cur];

        f32x4 sacc[4];
#pragma unroll
        for (int tt = 0; tt < 4; ++tt) {
            sacc[tt] = fzero;
            int rl = tt * 16 + lr;
#pragma unroll
            for (int kh = 0; kh < 2; ++kh) {
                int us = (kh * 4 + lg) ^ (rl & 7);
                bf16x8 kf = *(const bf16x8*)&KhiC[rl * 64 + us * 8];
                sacc[tt] = MFMA16(qh[kh], kf, sacc[tt]);
                sacc[tt] = MFMA16(ql[kh], kf, sacc[tt]);
            }
        }

#pragma unroll
        for (int c = 0; c < 5; ++c) {
            int tl = (wave + c) * 16 + lr;
            f32x4 cacc = fzero;
#pragma unroll
            for (int kh = 0; kh < 2; ++kh) {
                int us = (kh * 4 + lg) ^ (tl & 7);
                bf16x8 pfv = *(const bf16x8*)&PES[tl * 64 + us * 8];
                cacc = MFMA16(qh[kh], pfv, cacc);
            }
#pragma unroll
            for (int reg = 0; reg < 4; ++reg) {
                int row = rowbase + reg;
                int rl_c = row + 63 - tl;
                if ((unsigned)rl_c < 64u)
                    bb16[2 * (row * 64 + (rl_c ^ (((row >> 2) & 3) << 3)))] = f2bf(cacc[reg]);
            }
        }

        bf16x8 ka[2];
        {
            int rl = wave * 16 + lr;
#pragma unroll
            for (int kh = 0; kh < 2; ++kh) {
                int us = (kh * 4 + lg) ^ (rl & 7);
                ka[kh] = *(const bf16x8*)&KhiC[rl * 64 + us * 8];
            }
        }
#pragma unroll
        for (int c = 0; c < 5; ++c) {
            int tl = (3 - wave + c) * 16 + lr;
            f32x4 dacc = fzero;
#pragma unroll
            for (int kh = 0; kh < 2; ++kh) {
                int us = (kh * 4 + lg) ^ (tl & 7);
                bf16x8 pfv = *(const bf16x8*)&PES[tl * 64 + us * 8];
                dacc = MFMA16(ka[kh], pfv, dacc);
            }
#pragma unroll
            for (int reg = 0; reg < 4; ++reg) {
                int r_row = rowbase + reg;
                int ll_d = tl + r_row - 63;
                if ((unsigned)ll_d < 64u)
                    bb16[2 * (ll_d * 64 + (r_row ^ (((ll_d >> 2) & 3) << 3))) + 1]
                        = f2bf(dacc[reg] * SCALE);
            }
        }
        __syncthreads();   // BARRIER 1: bands visible; all PES(i)/KV(i) reads done

        if (it16 < 15) {
            stage_kv(r0 + 64, cur ^ 1);
            stage_pes(l0 - (r0 + 64) + 960);
        }

        float mask_v[4];
#pragma unroll
        for (int tt = 0; tt < 4; ++tt) mask_v[tt] = mask[b * 1024 + r0 + tt * 16 + lr];
#pragma unroll
        for (int reg = 0; reg < 4; ++reg) {
            int ll = rowbase + reg;
#pragma unroll
            for (int tt = 0; tt < 4; ++tt) {
                int rl = tt * 16 + lr;
                unsigned cd = bbS[ll * 64 + (rl ^ (((ll >> 2) & 3) << 3))];
                float cg = __builtin_bit_cast(float, cd << 16);
                float dg = __builtin_bit_cast(float, cd & 0xFFFF0000u);
                float p = __expf(sacc[tt][reg] + cg + dg + mask_v[tt]);
                l_r[reg] += p;
                PS[ll * 64 + (((rl >> 3) ^ (ll & 7)) << 3) + (rl & 7)] = f2bf(p);
            }
        }

        {
            int alr = wave * 16 + lr;
#pragma unroll
            for (int kh = 0; kh < 2; ++kh) {
                int usa = (kh * 4 + lg) ^ (alr & 7);
                bf16x8 pa = *(const bf16x8*)&PS[alr * 64 + usa * 8];
#pragma unroll
                for (int dt = 0; dt < 4; ++dt) {
                    int dl = dt * 16 + lr;
                    int usb = (kh * 4 + lg) ^ (dl & 7);
                    bf16x8 vf = *(const bf16x8*)&VtC[dl * 64 + usb * 8];
                    oacc[dt] = MFMA16(pa, vf, oacc[dt]);
                }
            }
        }
        __syncthreads();   // BARRIER 2: staging done
    }

    float inv[4];
#pragma unroll
    for (int reg = 0; reg < 4; ++reg) {
        float s = l_r[reg];
        s += __shfl_xor(s, 1);
        s += __shfl_xor(s, 2);
        s += __shfl_xor(s, 4);
        s += __shfl_xor(s, 8);
        inv[reg] = 1.0f / s;
    }
#pragma unroll
    for (int dt = 0; dt < 4; ++dt)
#pragma unroll
        for (int reg = 0; reg < 4; ++reg) {
            int ll = wave * 16 + lg * 4 + reg;
            int dl = dt * 16 + lr;
            out[((size_t)b * 1024 + l0 + ll) * 1024 + h * 64 + dl] = oacc[dt][reg] * inv[reg];
        }
}

extern "C" void kernel_launch(void* const* d_in, const int* in_sizes, int n_in,
                              void* d_out, int out_size, void* d_ws, size_t ws_size,
                              hipStream_t stream) {
    const float* hs   = (const float*)d_in[0];
    const float* mask = (const float*)d_in[1];
    const float* Wq   = (const float*)d_in[2];
    const float* bq   = (const float*)d_in[3];
    const float* Wk   = (const float*)d_in[4];
    const float* bk   = (const float*)d_in[5];
    const float* Wv   = (const float*)d_in[6];
    const float* bv   = (const float*)d_in[7];
    const float* de   = (const float*)d_in[8];
    float* out = (float*)d_out;

    const size_t per = (size_t)4 * 16 * 1024 * 64;   // 4.19M elems (= 4096*1024)
    unsigned short* Qhi  = (unsigned short*)d_ws;
    unsigned short* Qlo  = Qhi + per;
    unsigned short* Khi  = Qlo + per;
    unsigned short* Vtb  = Khi + per;
    unsigned short* Xhi  = Vtb + per;
    unsigned short* Xlo  = Xhi + per;
    unsigned short* Wthi = Xlo + per;
    unsigned short* de16 = Wthi + (size_t)3072 * 1024;

    conv_x<<<2048, 256, 0, stream>>>(hs, Xhi, Xlo);
    conv_w<<<dim3(16, 16, 3), 256, 0, stream>>>(Wq, Wk, Wv, Wthi);
    conv_de<<<64, 256, 0, stream>>>(de, de16);

    qkv_gemm<<<768, 256, 0, stream>>>(Xhi, Xlo, Wthi, bq, bk, bv,
                                      Qhi, Qlo, Khi, Vtb);

    attn_kernel<<<1024, 256, 0, stream>>>(Qhi, Qlo, Khi, Vtb, de16, mask, out);
}